// Round 17
// baseline (189.831 us; speedup 1.0000x reference)
//
#include <hip/hip_runtime.h>
#include <stdint.h>

typedef __attribute__((ext_vector_type(8))) short bf16x8;
typedef __attribute__((ext_vector_type(4))) float f32x4;

#define MFMA16(a, b, c) __builtin_amdgcn_mfma_f32_16x16x32_bf16((a), (b), (c), 0, 0, 0)

static __device__ __forceinline__ unsigned f2bf(float f) {
  union { float f; unsigned u; } cv;
  cv.f = f;
  return (cv.u + 0x7fffu + ((cv.u >> 16) & 1u)) >> 16;
}

#define BATCH 8192
#define ROWD  2128
#define HID   512
#define LATD  256
#define KC1   272            // 8-elem k-chunks for layer 1 (272*8 = 2176)
#define NTH   34             // 32-k tiles per K-half
#define HSL_TW (BATCH * HID) // ushorts per tower in a partial/h buffer

// ---------- prep: k-chunked transpose-cast (both weight mats, one launch) ----------
__device__ __forceinline__ void tcast_body(
    const float* __restrict__ in, unsigned short* __restrict__ o,
    int s, int N, int lgN, int Kin, int perm)
{
  const int kc = s >> lgN, n = s & (N - 1);
  unsigned short v[8];
#pragma unroll
  for (int e = 0; e < 8; ++e) {
    const int k = kc * 8 + e;
    float f = 0.0f;
    if (k < Kin) {
      const int src = perm ? (k < 128 ? k + 2000 : k - 128) : k;
      f = in[(size_t)src * N + n];
    }
    v[e] = (unsigned short)f2bf(f);
  }
  *(uint4*)(o + (size_t)s * 8) = *(const uint4*)v;
}

__global__ __launch_bounds__(256) void ASAECF_tcast(
    const float* __restrict__ uW1, const float* __restrict__ iW1,
    const float* __restrict__ uW2, const float* __restrict__ iW2,
    unsigned short* __restrict__ w1s, unsigned short* __restrict__ w2s)
{
  const int tower = blockIdx.z;
  const int s = blockIdx.x * 256 + threadIdx.x;
  if (blockIdx.y == 0) {
    tcast_body(tower ? iW1 : uW1, w1s + (size_t)tower * KC1 * HID * 8,
               s, HID, 9, ROWD, 1);
  } else {
    if (blockIdx.x >= 64) return;
    tcast_body(tower ? iW2 : uW2, w2s + (size_t)tower * 64 * LATD * 8,
               s, LATD, 8, HID, 0);
  }
}

// ---------- GEMM1 (split-K): partial = gather(look) @ W1p[khalf] ----------
// R14 skeleton: BM=128, BN=256 (nh), wave tile 128x32, B read once per block.
// SINGLE CHANGE: K split in two halves -> grid 512 = TWO co-resident blocks
// per CU (launch_bounds 4 waves/SIMD), same total traffic. kh=0 adds bias.
// Partials stored bf16 in the slot layout; combined in gemm2dot.
__global__ __launch_bounds__(512, 4) void ASAECF_gemm1(
    const int* __restrict__ x,
    const float* __restrict__ ulook, const float* __restrict__ ilook,
    const unsigned short* __restrict__ w1s,   // [2][KC1][512][8]
    const float* __restrict__ ub1, const float* __restrict__ ib1,
    unsigned short* __restrict__ hp0, unsigned short* __restrict__ hp1)
{
  const int bid   = blockIdx.x;             // 0..511
  const int xcd   = bid & 7;
  const int idx   = bid >> 3;               // 0..63
  const int tower = xcd >> 2;
  const int kh    = idx & 1;                // K-half; pair co-resident on CU
  const int nh    = (idx >> 1) & 1;         // N-half; pair shares gather rows
  const int mb    = (xcd & 3) * 16 + (idx >> 2);   // 0..63

  const float* __restrict__ look = tower ? ilook : ulook;
  const unsigned short* __restrict__ w1 = w1s + (size_t)tower * KC1 * HID * 8;
  const float* __restrict__ b1 = tower ? ib1 : ub1;
  unsigned short* __restrict__ hout =
      (kh ? hp1 : hp0) + (size_t)tower * HSL_TW;

  __shared__ unsigned short Ab[2][128 * 40];  // 128 rows x 32 k, 80-B pitch

  const int tid  = threadIdx.x;
  const int lane = tid & 63, wid = tid >> 6;  // wid 0..7 -> 32-col B slice
  const int fr   = lane & 15, fq = lane >> 4;
  const int row0 = mb * 128;

  // A staging: thread -> (row ar, 8 consecutive k at ak)
  const int ar = tid >> 2, ak = (tid & 3) * 8;
  const long long arow = (long long)x[(row0 + ar) * 2 + tower] * ROWD + ak;

  int boff[2];
#pragma unroll
  for (int n = 0; n < 2; ++n)
    boff[n] = (fq * 512 + nh * 256 + wid * 32 + n * 16 + fr) * 8;

  struct A8 { f32x4 a, b; };
  auto loadA = [&](int tt) -> A8 {
    A8 v;
    v.a = f32x4{0.0f, 0.0f, 0.0f, 0.0f};
    v.b = f32x4{0.0f, 0.0f, 0.0f, 0.0f};
    if (tt * 32 + ak + 8 <= ROWD) {
      v.a = *(const f32x4*)(look + arow + tt * 32);
      v.b = *(const f32x4*)(look + arow + tt * 32 + 4);
    }
    return v;
  };
  auto writeA = [&](int buf, A8 v) {
    uint2 p, q;
    p.x = f2bf(v.a[0]) | (f2bf(v.a[1]) << 16);
    p.y = f2bf(v.a[2]) | (f2bf(v.a[3]) << 16);
    q.x = f2bf(v.b[0]) | (f2bf(v.b[1]) << 16);
    q.y = f2bf(v.b[2]) | (f2bf(v.b[3]) << 16);
    *(uint2*)&Ab[buf][ar * 40 + ak] = p;
    *(uint2*)&Ab[buf][ar * 40 + ak + 4] = q;
  };

  f32x4 acc[8][2] = {};
  bf16x8 bgc[2], bgn[2];
  A8 rA0, rA1;

  const int t0 = kh * NTH;                  // even for both kh
  writeA(0, loadA(t0));
  rA0 = loadA(t0 + 1);
  rA1 = loadA(t0 + 2);
#pragma unroll
  for (int n = 0; n < 2; ++n)
    bgc[n] = *(const bf16x8*)(w1 + (size_t)t0 * (4 * 512 * 8) + boff[n]);

#pragma unroll 2
  for (int t = t0; t < t0 + NTH; ++t) {
    __syncthreads();
    const int cu = t & 1;

    const unsigned short* bpn = w1 + (size_t)(t + 1) * (4 * 512 * 8);
#pragma unroll
    for (int n = 0; n < 2; ++n) bgn[n] = *(const bf16x8*)(bpn + boff[n]);

    bf16x8 af[8];
#pragma unroll
    for (int m = 0; m < 8; ++m)
      af[m] = *(const bf16x8*)&Ab[cu][(m * 16 + fr) * 40 + fq * 8];
#pragma unroll
    for (int n = 0; n < 2; ++n)
#pragma unroll
      for (int m = 0; m < 8; ++m)
        acc[m][n] = MFMA16(af[m], bgc[n], acc[m][n]);

    if (cu == (t0 & 1)) { writeA(1 ^ (t0 & 1), rA0); rA0 = loadA(t + 3); }
    else                { writeA(t0 & 1, rA1);       rA1 = loadA(t + 3); }

#pragma unroll
    for (int n = 0; n < 2; ++n) bgc[n] = bgn[n];
  }

  // epilogue: (+bias if kh==0), NO relu, bf16 partial in slot layout
#pragma unroll
  for (int n = 0; n < 2; ++n) {
    const int col = nh * 256 + wid * 32 + n * 16 + fr;
    const int kc = col >> 3, e = col & 7;
    const float bb = kh ? 0.0f : b1[col];
#pragma unroll
    for (int m = 0; m < 8; ++m)
#pragma unroll
      for (int i = 0; i < 4; ++i) {
        const int rowib = m * 16 + fq * 4 + i;
        const int chunk = mb * 2 + (rowib >> 6);
        const int row = rowib & 63;
        hout[(((size_t)chunk * 64 + kc) * 64 + row) * 8 + e] =
            (unsigned short)f2bf(acc[m][n][i] + bb);
      }
  }
}

// ---------- GEMM2 + dot, combining the two K-half partials ----------
__global__ __launch_bounds__(512, 2) void ASAECF_gemm2dot(
    const unsigned short* __restrict__ hp0,   // [2][chunk64][kc][row64][8]
    const unsigned short* __restrict__ hp1,
    const unsigned short* __restrict__ w2s,   // [2][64][256][8]
    const float* __restrict__ ub2, const float* __restrict__ ib2,
    float* __restrict__ out)
{
  const int tid  = threadIdx.x;
  const int lane = tid & 63, wid = tid >> 6;
  const int fr   = lane & 15, fq = lane >> 4;
  const int rb   = blockIdx.x;          // 32-row block
  const int row0 = rb * 32;

  const size_t abase = ((size_t)(rb >> 1) * 64) * 64 * 8;
  const int lrow0 = (rb & 1) * 32;

  // combine two bf16x8 partials: relu(p0+p1), truncating repack to bf16
  auto combine = [&](bf16x8 p0, bf16x8 p1) -> bf16x8 {
    union { bf16x8 v; unsigned u[4]; } a, b, r;
    a.v = p0; b.v = p1;
#pragma unroll
    for (int j = 0; j < 4; ++j) {
      union { float f; unsigned u; } x0, x1, y0, y1;
      x0.u = a.u[j] << 16;       x1.u = a.u[j] & 0xffff0000u;
      y0.u = b.u[j] << 16;       y1.u = b.u[j] & 0xffff0000u;
      float lo = fmaxf(x0.f + y0.f, 0.0f);
      float hi = fmaxf(x1.f + y1.f, 0.0f);
      union { float f; unsigned u; } lu, hu2;
      lu.f = lo; hu2.f = hi;
      r.u[j] = (lu.u >> 16) | (hu2.u & 0xffff0000u);
    }
    return r.v;
  };

  f32x4 au[2][2] = {}, av[2][2] = {};

#pragma unroll
  for (int t = 0; t < 8; ++t) {
#pragma unroll
    for (int s = 0; s < 2; ++s) {
      const int kc = t * 8 + s * 4 + fq;
      bf16x8 a_u[2], a_v[2], b_u[2], b_v[2];
#pragma unroll
      for (int m = 0; m < 2; ++m) {
        const size_t off = abase + ((size_t)kc * 64 + lrow0 + m * 16 + fr) * 8;
        a_u[m] = combine(*(const bf16x8*)(hp0 + off),
                         *(const bf16x8*)(hp1 + off));
        a_v[m] = combine(*(const bf16x8*)(hp0 + (size_t)HSL_TW + off),
                         *(const bf16x8*)(hp1 + (size_t)HSL_TW + off));
      }
#pragma unroll
      for (int n = 0; n < 2; ++n) {
        const int col = wid * 32 + n * 16 + fr;
        const size_t offb = ((size_t)kc * 256 + col) * 8;
        b_u[n] = *(const bf16x8*)(w2s + offb);
        b_v[n] = *(const bf16x8*)(w2s + (size_t)64 * 256 * 8 + offb);
      }
#pragma unroll
      for (int m = 0; m < 2; ++m)
#pragma unroll
        for (int n = 0; n < 2; ++n) {
          au[m][n] = MFMA16(a_u[m], b_u[n], au[m][n]);
          av[m][n] = MFMA16(a_v[m], b_v[n], av[m][n]);
        }
    }
  }

  __shared__ float red[8][32];
  float bu[2], bv[2];
#pragma unroll
  for (int n = 0; n < 2; ++n) {
    const int col = wid * 32 + n * 16 + fr;
    bu[n] = ub2[col];
    bv[n] = ib2[col];
  }
#pragma unroll
  for (int m = 0; m < 2; ++m)
#pragma unroll
    for (int i = 0; i < 4; ++i) {
      float p = 0.0f;
#pragma unroll
      for (int n = 0; n < 2; ++n)
        p += (au[m][n][i] + bu[n]) * (av[m][n][i] + bv[n]);
      p += __shfl_xor(p, 1, 64);
      p += __shfl_xor(p, 2, 64);
      p += __shfl_xor(p, 4, 64);
      p += __shfl_xor(p, 8, 64);
      if (fr == 0) red[wid][m * 16 + fq * 4 + i] = p;
    }
  __syncthreads();
  if (tid < 32) {
    float s = 0.0f;
#pragma unroll
    for (int w = 0; w < 8; ++w) s += red[w][tid];
    out[row0 + tid] = s;
  }
}

extern "C" void kernel_launch(void* const* d_in, const int* in_sizes, int n_in,
                              void* d_out, int out_size, void* d_ws, size_t ws_size,
                              hipStream_t stream) {
  (void)in_sizes; (void)n_in; (void)out_size; (void)ws_size;
  const int*   x     = (const int*)d_in[0];
  const float* ulook = (const float*)d_in[1];
  const float* ilook = (const float*)d_in[2];
  const float* uW1   = (const float*)d_in[3];
  const float* ub1   = (const float*)d_in[4];
  const float* uW2   = (const float*)d_in[5];
  const float* ub2   = (const float*)d_in[6];
  const float* iW1   = (const float*)d_in[7];
  const float* ib1   = (const float*)d_in[8];
  const float* iW2   = (const float*)d_in[9];
  const float* ib2   = (const float*)d_in[10];
  float* out = (float*)d_out;

  // workspace layout (bytes):
  //   w1s: [2][272][512][8] bf16 = 4,456,448
  //   w2s: [2][64][256][8]  bf16 =   524,288  @  4,456,448
  //   hp0: [2][8192*512]    bf16 = 16,777,216 @  4,980,736
  //   hp1: [2][8192*512]    bf16 = 16,777,216 @ 21,757,952
  char* ws = (char*)d_ws;
  unsigned short* w1s = (unsigned short*)(ws);
  unsigned short* w2s = (unsigned short*)(ws + 4456448);
  unsigned short* hp0 = (unsigned short*)(ws + 4980736);
  unsigned short* hp1 = (unsigned short*)(ws + 21757952);

  ASAECF_tcast<<<dim3(544, 2, 2), 256, 0, stream>>>(uW1, iW1, uW2, iW2, w1s, w2s);
  ASAECF_gemm1<<<dim3(512), 512, 0, stream>>>(x, ulook, ilook, w1s, ub1, ib1, hp0, hp1);
  ASAECF_gemm2dot<<<dim3(256), 512, 0, stream>>>(hp0, hp1, w2s, ub2, ib2, out);
}

// Round 18
// 128.094 us; speedup vs baseline: 1.4820x; 1.4820x over previous
//
#include <hip/hip_runtime.h>
#include <stdint.h>

typedef __attribute__((ext_vector_type(8))) short bf16x8;
typedef __attribute__((ext_vector_type(4))) float f32x4;

#define MFMA16(a, b, c) __builtin_amdgcn_mfma_f32_16x16x32_bf16((a), (b), (c), 0, 0, 0)

static __device__ __forceinline__ unsigned f2bf(float f) {
  union { float f; unsigned u; } cv;
  cv.f = f;
  return (cv.u + 0x7fffu + ((cv.u >> 16) & 1u)) >> 16;
}

#define BATCH 8192
#define ROWD  2128
#define HID   512
#define LATD  256
#define KC1   272            // 8-elem k-chunks for layer 1 (272*8 = 2176)
#define NCH   17             // 128-k chunks
#define SLAB  16384          // ushorts per 32-k B slab (4*512*8)
#define APITCH 136           // ushorts per A row in LDS (272 B, bank-safe)
#define HSL_TW (BATCH * HID) // ushorts per tower in h_sl

// ---------- prep: k-chunked transpose-cast (both weight mats, one launch) ----------
__device__ __forceinline__ void tcast_body(
    const float* __restrict__ in, unsigned short* __restrict__ o,
    int s, int N, int lgN, int Kin, int perm)
{
  const int kc = s >> lgN, n = s & (N - 1);
  unsigned short v[8];
#pragma unroll
  for (int e = 0; e < 8; ++e) {
    const int k = kc * 8 + e;
    float f = 0.0f;
    if (k < Kin) {
      const int src = perm ? (k < 128 ? k + 2000 : k - 128) : k;
      f = in[(size_t)src * N + n];
    }
    v[e] = (unsigned short)f2bf(f);
  }
  *(uint4*)(o + (size_t)s * 8) = *(const uint4*)v;
}

__global__ __launch_bounds__(256) void ASAECF_tcast(
    const float* __restrict__ uW1, const float* __restrict__ iW1,
    const float* __restrict__ uW2, const float* __restrict__ iW2,
    unsigned short* __restrict__ w1s, unsigned short* __restrict__ w2s)
{
  const int tower = blockIdx.z;
  const int s = blockIdx.x * 256 + threadIdx.x;
  if (blockIdx.y == 0) {
    tcast_body(tower ? iW1 : uW1, w1s + (size_t)tower * KC1 * HID * 8,
               s, HID, 9, ROWD, 1);
  } else {
    if (blockIdx.x >= 64) return;
    tcast_body(tower ? iW2 : uW2, w2s + (size_t)tower * 64 * LATD * 8,
               s, LATD, 8, HID, 0);
  }
}

// ---------- GEMM1: h = relu(gather(look) @ W1p + b1) ----------
// BM=128, BN=256 (nh half), 8 waves, wave tile 64x64 (2M x 4N -> LDS-A reads
// halved vs 128x32), K chunked by 128 with double-buffered LDS: ONE barrier
// per chunk (17 total). Gather loads for chunk c+1 issue at the START of
// chunk c's compute (64 MFMA/wave of cover); cvt+ds_write land at the end.
// B: per-32k-tile register prefetch from L2-resident w1s (R14 traffic).
__global__ __launch_bounds__(512) void ASAECF_gemm1(
    const int* __restrict__ x,
    const float* __restrict__ ulook, const float* __restrict__ ilook,
    const unsigned short* __restrict__ w1s,   // [2][KC1][512][8]
    const float* __restrict__ ub1, const float* __restrict__ ib1,
    unsigned short* __restrict__ hsl)         // [2][chunk64][kc][row64][8]
{
  __shared__ unsigned short Ab[2][128 * APITCH];   // 2 x 34.8 KB

  const int bid   = blockIdx.x;             // 0..255
  const int xcd   = bid & 7;
  const int idx   = bid >> 3;               // 0..31
  const int tower = xcd >> 2;
  const int nh    = idx & 1;                // nh pair adjacent on same XCD
  const int mb    = (xcd & 3) * 16 + (idx >> 1);   // 0..63

  const float* __restrict__ look = tower ? ilook : ulook;
  const unsigned short* __restrict__ w1 = w1s + (size_t)tower * KC1 * HID * 8;
  const float* __restrict__ b1 = tower ? ib1 : ub1;
  unsigned short* __restrict__ hout = hsl + (size_t)tower * HSL_TW;

  const int tid  = threadIdx.x;
  const int lane = tid & 63, wid = tid >> 6;
  const int wm   = wid >> 2, wn = wid & 3;    // wave tile: rows wm*64, cols wn*64
  const int fr   = lane & 15, fq = lane >> 4;
  const int row0 = mb * 128;

  // A staging: thread -> (row ar, 32 consecutive k at akc within chunk)
  const int ar  = tid >> 2;                  // 0..127
  const int akc = (tid & 3) * 32;            // 0,32,64,96
  const long long arow = (long long)x[(row0 + ar) * 2 + tower] * ROWD;

  // B fragment offsets within one 32-k slab
  int boff[4];
#pragma unroll
  for (int n = 0; n < 4; ++n)
    boff[n] = (fq * 512 + nh * 256 + wn * 64 + n * 16 + fr) * 8;

  f32x4 rA[8];
  auto loadA = [&](int c) {                  // chunk c: k base c*128 + akc
    const long long kb = (long long)c * 128 + akc;
#pragma unroll
    for (int j = 0; j < 8; ++j) {
      rA[j] = f32x4{0.0f, 0.0f, 0.0f, 0.0f};
      if (kb + j * 4 + 4 <= ROWD)
        rA[j] = *(const f32x4*)(look + arow + kb + j * 4);
    }
  };
  auto writeA = [&](int buf) {
    unsigned short* d = &Ab[buf][ar * APITCH + akc];
#pragma unroll
    for (int j2 = 0; j2 < 4; ++j2) {
      union { unsigned u[4]; bf16x8 v; } p;
      p.u[0] = f2bf(rA[2 * j2][0])     | (f2bf(rA[2 * j2][1]) << 16);
      p.u[1] = f2bf(rA[2 * j2][2])     | (f2bf(rA[2 * j2][3]) << 16);
      p.u[2] = f2bf(rA[2 * j2 + 1][0]) | (f2bf(rA[2 * j2 + 1][1]) << 16);
      p.u[3] = f2bf(rA[2 * j2 + 1][2]) | (f2bf(rA[2 * j2 + 1][3]) << 16);
      *(bf16x8*)(d + j2 * 8) = p.v;
    }
  };

  f32x4 acc[4][4] = {};
  bf16x8 bgc[4], bgn[4];

  // prologue: chunk 0 staged into buf 0; B slab 0 in flight
  loadA(0);
  writeA(0);
#pragma unroll
  for (int n = 0; n < 4; ++n) bgc[n] = *(const bf16x8*)(w1 + boff[n]);
  __syncthreads();

  for (int c = 0; c < NCH; ++c) {
    const int cu = c & 1;
    const bool pre = (c + 1 < NCH);
    if (pre) loadA(c + 1);                   // issue-early (T14)

#pragma unroll
    for (int tt = 0; tt < 4; ++tt) {
      const int t = c * 4 + tt;
      // B prefetch for tile t+1 (counted vmcnt; never blocks this tile)
      const unsigned short* bpn = w1 + (size_t)(t + 1) * SLAB;
#pragma unroll
      for (int n = 0; n < 4; ++n) bgn[n] = *(const bf16x8*)(bpn + boff[n]);

      bf16x8 af[4];
#pragma unroll
      for (int m = 0; m < 4; ++m)
        af[m] = *(const bf16x8*)&Ab[cu][(wm * 64 + m * 16 + fr) * APITCH + tt * 32 + fq * 8];
#pragma unroll
      for (int n = 0; n < 4; ++n)
#pragma unroll
        for (int m = 0; m < 4; ++m)
          acc[m][n] = MFMA16(af[m], bgc[n], acc[m][n]);

#pragma unroll
      for (int n = 0; n < 4; ++n) bgc[n] = bgn[n];
    }

    if (pre) writeA(cu ^ 1);                 // write-late (T14)
    __syncthreads();                         // chunk boundary (only barrier)
  }

  // epilogue: bias + relu + store h in k-chunked slot layout
#pragma unroll
  for (int n = 0; n < 4; ++n) {
    const int col = nh * 256 + wn * 64 + n * 16 + fr;
    const int kc = col >> 3, e = col & 7;
    const float bb = b1[col];
#pragma unroll
    for (int m = 0; m < 4; ++m)
#pragma unroll
      for (int i = 0; i < 4; ++i) {
        const int rowib = wm * 64 + m * 16 + fq * 4 + i;   // 0..127 in block
        const int chunk = mb * 2 + (rowib >> 6);
        const int row = rowib & 63;
        const float v = fmaxf(acc[m][n][i] + bb, 0.0f);
        hout[(((size_t)chunk * 64 + kc) * 64 + row) * 8 + e] = (unsigned short)f2bf(v);
      }
  }
}

// ---------- GEMM2 + dot, fully fused, no LDS staging ----------
__global__ __launch_bounds__(512, 2) void ASAECF_gemm2dot(
    const unsigned short* __restrict__ hsl,   // [2][chunk64][kc][row64][8]
    const unsigned short* __restrict__ w2s,   // [2][64][256][8]
    const float* __restrict__ ub2, const float* __restrict__ ib2,
    float* __restrict__ out)
{
  const int tid  = threadIdx.x;
  const int lane = tid & 63, wid = tid >> 6;
  const int fr   = lane & 15, fq = lane >> 4;
  const int rb   = blockIdx.x;          // 32-row block
  const int row0 = rb * 32;

  const unsigned short* __restrict__ hu = hsl;
  const unsigned short* __restrict__ hv = hsl + (size_t)HSL_TW;
  const size_t abase = ((size_t)(rb >> 1) * 64) * 64 * 8;
  const int lrow0 = (rb & 1) * 32;

  f32x4 au[2][2] = {}, av[2][2] = {};

#pragma unroll
  for (int t = 0; t < 8; ++t) {
#pragma unroll
    for (int s = 0; s < 2; ++s) {
      const int kc = t * 8 + s * 4 + fq;
      bf16x8 a_u[2], a_v[2], b_u[2], b_v[2];
#pragma unroll
      for (int m = 0; m < 2; ++m) {
        const size_t off = abase + ((size_t)kc * 64 + lrow0 + m * 16 + fr) * 8;
        a_u[m] = *(const bf16x8*)(hu + off);
        a_v[m] = *(const bf16x8*)(hv + off);
      }
#pragma unroll
      for (int n = 0; n < 2; ++n) {
        const int col = wid * 32 + n * 16 + fr;
        const size_t offb = ((size_t)kc * 256 + col) * 8;
        b_u[n] = *(const bf16x8*)(w2s + offb);
        b_v[n] = *(const bf16x8*)(w2s + (size_t)64 * 256 * 8 + offb);
      }
#pragma unroll
      for (int m = 0; m < 2; ++m)
#pragma unroll
        for (int n = 0; n < 2; ++n) {
          au[m][n] = MFMA16(a_u[m], b_u[n], au[m][n]);
          av[m][n] = MFMA16(a_v[m], b_v[n], av[m][n]);
        }
    }
  }

  // bias + per-row dot + reduction
  __shared__ float red[8][32];
  float bu[2], bv[2];
#pragma unroll
  for (int n = 0; n < 2; ++n) {
    const int col = wid * 32 + n * 16 + fr;
    bu[n] = ub2[col];
    bv[n] = ib2[col];
  }
#pragma unroll
  for (int m = 0; m < 2; ++m)
#pragma unroll
    for (int i = 0; i < 4; ++i) {
      float p = 0.0f;
#pragma unroll
      for (int n = 0; n < 2; ++n)
        p += (au[m][n][i] + bu[n]) * (av[m][n][i] + bv[n]);
      p += __shfl_xor(p, 1, 64);
      p += __shfl_xor(p, 2, 64);
      p += __shfl_xor(p, 4, 64);
      p += __shfl_xor(p, 8, 64);
      if (fr == 0) red[wid][m * 16 + fq * 4 + i] = p;
    }
  __syncthreads();
  if (tid < 32) {
    float s = 0.0f;
#pragma unroll
    for (int w = 0; w < 8; ++w) s += red[w][tid];
    out[row0 + tid] = s;
  }
}

extern "C" void kernel_launch(void* const* d_in, const int* in_sizes, int n_in,
                              void* d_out, int out_size, void* d_ws, size_t ws_size,
                              hipStream_t stream) {
  (void)in_sizes; (void)n_in; (void)out_size; (void)ws_size;
  const int*   x     = (const int*)d_in[0];
  const float* ulook = (const float*)d_in[1];
  const float* ilook = (const float*)d_in[2];
  const float* uW1   = (const float*)d_in[3];
  const float* ub1   = (const float*)d_in[4];
  const float* uW2   = (const float*)d_in[5];
  const float* ub2   = (const float*)d_in[6];
  const float* iW1   = (const float*)d_in[7];
  const float* ib1   = (const float*)d_in[8];
  const float* iW2   = (const float*)d_in[9];
  const float* ib2   = (const float*)d_in[10];
  float* out = (float*)d_out;

  // workspace layout (bytes):
  //   w1s: [2][272][512][8] bf16 = 4,456,448
  //   w2s: [2][64][256][8]  bf16 =   524,288  @ 4,456,448
  //   hsl: [2][8192*512]    bf16 = 16,777,216 @ 4,980,736
  char* ws = (char*)d_ws;
  unsigned short* w1s = (unsigned short*)(ws);
  unsigned short* w2s = (unsigned short*)(ws + 4456448);
  unsigned short* hsl = (unsigned short*)(ws + 4980736);

  ASAECF_tcast<<<dim3(544, 2, 2), 256, 0, stream>>>(uW1, iW1, uW2, iW2, w1s, w2s);
  ASAECF_gemm1<<<dim3(256), 512, 0, stream>>>(x, ulook, ilook, w1s, ub1, ib1, hsl);
  ASAECF_gemm2dot<<<dim3(256), 512, 0, stream>>>(hsl, w2s, ub2, ib2, out);
}

// Round 19
// 78.035 us; speedup vs baseline: 2.4326x; 1.6415x over previous
//
#include <hip/hip_runtime.h>
#include <stdint.h>

typedef __attribute__((ext_vector_type(8))) short bf16x8;
typedef __attribute__((ext_vector_type(4))) float f32x4;

#define MFMA16(a, b, c) __builtin_amdgcn_mfma_f32_16x16x32_bf16((a), (b), (c), 0, 0, 0)

static __device__ __forceinline__ unsigned f2bf(float f) {
  union { float f; unsigned u; } cv;
  cv.f = f;
  return (cv.u + 0x7fffu + ((cv.u >> 16) & 1u)) >> 16;
}

#define BATCH 8192
#define ROWD  2128
#define HID   512
#define LATD  256
#define KC1   272            // 8-elem k-chunks for layer 1 (272*8 = 2176, zero-padded)
#define NT1   68             // 32-k tiles (68*32 = 2176; trailing tiles zero-padded)
#define HSL_TW (BATCH * HID) // ushorts per tower in h_sl

// ---------- prep: k-chunked transpose-cast (both weight mats, one launch) ----------
__device__ __forceinline__ void tcast_body(
    const float* __restrict__ in, unsigned short* __restrict__ o,
    int s, int N, int lgN, int Kin, int perm)
{
  const int kc = s >> lgN, n = s & (N - 1);
  unsigned short v[8];
#pragma unroll
  for (int e = 0; e < 8; ++e) {
    const int k = kc * 8 + e;
    float f = 0.0f;
    if (k < Kin) {
      const int src = perm ? (k < 128 ? k + 2000 : k - 128) : k;
      f = in[(size_t)src * N + n];
    }
    v[e] = (unsigned short)f2bf(f);
  }
  *(uint4*)(o + (size_t)s * 8) = *(const uint4*)v;
}

__global__ __launch_bounds__(256) void ASAECF_tcast(
    const float* __restrict__ uW1, const float* __restrict__ iW1,
    const float* __restrict__ uW2, const float* __restrict__ iW2,
    unsigned short* __restrict__ w1s, unsigned short* __restrict__ w2s)
{
  const int tower = blockIdx.z;
  const int s = blockIdx.x * 256 + threadIdx.x;
  if (blockIdx.y == 0) {
    tcast_body(tower ? iW1 : uW1, w1s + (size_t)tower * KC1 * HID * 8,
               s, HID, 9, ROWD, 1);
  } else {
    if (blockIdx.x >= 64) return;
    tcast_body(tower ? iW2 : uW2, w2s + (size_t)tower * 64 * LATD * 8,
               s, LATD, 8, HID, 0);
  }
}

// ---------- GEMM1: h = relu(gather(look) @ W1p + b1) ----------
// BM=128, BN=256 (nh half), BK=32. 512 thr = 8 waves, wave tile 128x32
// (af[8], bg[2]): every wave covers all 128 rows and a DISTINCT 32-col
// slice, so B fragments are read once per block (chip 143 MB L2 traffic).
// A: random-row gather pipelined 2 tiles ahead in regs, LDS double-buffered.
// Grid = 64 mb x 2 nh x 2 towers = 256 blocks (1/CU), nh pair on same XCD.
__global__ __launch_bounds__(512) void ASAECF_gemm1(
    const int* __restrict__ x,
    const float* __restrict__ ulook, const float* __restrict__ ilook,
    const unsigned short* __restrict__ w1s,   // [2][KC1][512][8]
    const float* __restrict__ ub1, const float* __restrict__ ib1,
    unsigned short* __restrict__ hsl)         // [2][chunk64][kc][row64][8]
{
  const int bid   = blockIdx.x;             // 0..255
  const int xcd   = bid & 7;
  const int idx   = bid >> 3;               // 0..31
  const int tower = xcd >> 2;
  const int nh    = idx & 1;
  const int mb    = (xcd & 3) * 16 + (idx >> 1);   // 0..63

  const float* __restrict__ look = tower ? ilook : ulook;
  const unsigned short* __restrict__ w1 = w1s + (size_t)tower * KC1 * HID * 8;
  const float* __restrict__ b1 = tower ? ib1 : ub1;
  unsigned short* __restrict__ hout = hsl + (size_t)tower * HSL_TW;

  __shared__ unsigned short Ab[2][128 * 40];  // 128 rows x 32 k, 80-B padded rows

  const int tid  = threadIdx.x;
  const int lane = tid & 63, wid = tid >> 6;  // wid 0..7 -> 32-col B slice
  const int fr   = lane & 15, fq = lane >> 4;
  const int row0 = mb * 128;

  // A staging: thread -> (row ar, 8 consecutive k at ak)
  const int ar = tid >> 2, ak = (tid & 3) * 8;
  const long long arow = (long long)x[(row0 + ar) * 2 + tower] * ROWD + ak;

  // B fragment offsets within one k-tile slab (4*512*8 ushorts)
  int boff[2];
#pragma unroll
  for (int n = 0; n < 2; ++n)
    boff[n] = (fq * 512 + nh * 256 + wid * 32 + n * 16 + fr) * 8;

  struct A8 { f32x4 a, b; };
  auto loadA = [&](int tt) -> A8 {
    A8 v;
    v.a = f32x4{0.0f, 0.0f, 0.0f, 0.0f};
    v.b = f32x4{0.0f, 0.0f, 0.0f, 0.0f};
    if (tt * 32 + ak + 8 <= ROWD) {
      v.a = *(const f32x4*)(look + arow + tt * 32);
      v.b = *(const f32x4*)(look + arow + tt * 32 + 4);
    }
    return v;
  };
  auto writeA = [&](int buf, A8 v) {
    uint2 p, q;
    p.x = f2bf(v.a[0]) | (f2bf(v.a[1]) << 16);
    p.y = f2bf(v.a[2]) | (f2bf(v.a[3]) << 16);
    q.x = f2bf(v.b[0]) | (f2bf(v.b[1]) << 16);
    q.y = f2bf(v.b[2]) | (f2bf(v.b[3]) << 16);
    *(uint2*)&Ab[buf][ar * 40 + ak] = p;
    *(uint2*)&Ab[buf][ar * 40 + ak + 4] = q;
  };

  f32x4 acc[8][2] = {};
  bf16x8 bgc[2], bgn[2];
  A8 rA0, rA1;

  // prologue: A(0) -> Ab[0]; A(1),A(2) in flight; B(0) in flight
  writeA(0, loadA(0));
  rA0 = loadA(1);
  rA1 = loadA(2);
#pragma unroll
  for (int n = 0; n < 2; ++n) bgc[n] = *(const bf16x8*)(w1 + boff[n]);

#pragma unroll 2
  for (int t = 0; t < NT1; ++t) {
    __syncthreads();   // Ab[t&1] ready
    const int cu = t & 1;

    // B prefetch for t+1 (stays in flight through this tile's MFMAs)
    const unsigned short* bpn = w1 + (size_t)(t + 1) * (4 * 512 * 8);
#pragma unroll
    for (int n = 0; n < 2; ++n) bgn[n] = *(const bf16x8*)(bpn + boff[n]);

    bf16x8 af[8];
#pragma unroll
    for (int m = 0; m < 8; ++m)
      af[m] = *(const bf16x8*)&Ab[cu][(m * 16 + fr) * 40 + fq * 8];
#pragma unroll
    for (int n = 0; n < 2; ++n)
#pragma unroll
      for (int m = 0; m < 8; ++m)
        acc[m][n] = MFMA16(af[m], bgc[n], acc[m][n]);

    // deferred A write (loaded 2 tiles ago), then refill the pipe
    if (cu == 0) { writeA(1, rA0); rA0 = loadA(t + 3); }
    else         { writeA(0, rA1); rA1 = loadA(t + 3); }

#pragma unroll
    for (int n = 0; n < 2; ++n) bgc[n] = bgn[n];
  }

  // epilogue: bias + relu + store h in k-chunked slot layout
#pragma unroll
  for (int n = 0; n < 2; ++n) {
    const int col = nh * 256 + wid * 32 + n * 16 + fr;
    const int kc = col >> 3, e = col & 7;
    const float bb = b1[col];
#pragma unroll
    for (int m = 0; m < 8; ++m)
#pragma unroll
      for (int i = 0; i < 4; ++i) {
        const int rowib = m * 16 + fq * 4 + i;          // 0..127 within block
        const int chunk = mb * 2 + (rowib >> 6);
        const int row = rowib & 63;
        const float v = fmaxf(acc[m][n][i] + bb, 0.0f);
        hout[(((size_t)chunk * 64 + kc) * 64 + row) * 8 + e] = (unsigned short)f2bf(v);
      }
  }
}

// ---------- GEMM2 + dot, fully fused, no LDS staging ----------
__global__ __launch_bounds__(512, 2) void ASAECF_gemm2dot(
    const unsigned short* __restrict__ hsl,   // [2][chunk64][kc][row64][8]
    const unsigned short* __restrict__ w2s,   // [2][64][256][8]
    const float* __restrict__ ub2, const float* __restrict__ ib2,
    float* __restrict__ out)
{
  const int tid  = threadIdx.x;
  const int lane = tid & 63, wid = tid >> 6;
  const int fr   = lane & 15, fq = lane >> 4;
  const int rb   = blockIdx.x;          // 32-row block
  const int row0 = rb * 32;

  const unsigned short* __restrict__ hu = hsl;
  const unsigned short* __restrict__ hv = hsl + (size_t)HSL_TW;
  const size_t abase = ((size_t)(rb >> 1) * 64) * 64 * 8;
  const int lrow0 = (rb & 1) * 32;

  f32x4 au[2][2] = {}, av[2][2] = {};

#pragma unroll
  for (int t = 0; t < 8; ++t) {
#pragma unroll
    for (int s = 0; s < 2; ++s) {
      const int kc = t * 8 + s * 4 + fq;
      bf16x8 a_u[2], a_v[2], b_u[2], b_v[2];
#pragma unroll
      for (int m = 0; m < 2; ++m) {
        const size_t off = abase + ((size_t)kc * 64 + lrow0 + m * 16 + fr) * 8;
        a_u[m] = *(const bf16x8*)(hu + off);
        a_v[m] = *(const bf16x8*)(hv + off);
      }
#pragma unroll
      for (int n = 0; n < 2; ++n) {
        const int col = wid * 32 + n * 16 + fr;
        const size_t offb = ((size_t)kc * 256 + col) * 8;
        b_u[n] = *(const bf16x8*)(w2s + offb);
        b_v[n] = *(const bf16x8*)(w2s + (size_t)64 * 256 * 8 + offb);
      }
#pragma unroll
      for (int m = 0; m < 2; ++m)
#pragma unroll
        for (int n = 0; n < 2; ++n) {
          au[m][n] = MFMA16(a_u[m], b_u[n], au[m][n]);
          av[m][n] = MFMA16(a_v[m], b_v[n], av[m][n]);
        }
    }
  }

  // bias + per-row dot + reduction
  __shared__ float red[8][32];
  float bu[2], bv[2];
#pragma unroll
  for (int n = 0; n < 2; ++n) {
    const int col = wid * 32 + n * 16 + fr;
    bu[n] = ub2[col];
    bv[n] = ib2[col];
  }
#pragma unroll
  for (int m = 0; m < 2; ++m)
#pragma unroll
    for (int i = 0; i < 4; ++i) {
      float p = 0.0f;
#pragma unroll
      for (int n = 0; n < 2; ++n)
        p += (au[m][n][i] + bu[n]) * (av[m][n][i] + bv[n]);
      p += __shfl_xor(p, 1, 64);
      p += __shfl_xor(p, 2, 64);
      p += __shfl_xor(p, 4, 64);
      p += __shfl_xor(p, 8, 64);
      if (fr == 0) red[wid][m * 16 + fq * 4 + i] = p;
    }
  __syncthreads();
  if (tid < 32) {
    float s = 0.0f;
#pragma unroll
    for (int w = 0; w < 8; ++w) s += red[w][tid];
    out[row0 + tid] = s;
  }
}

extern "C" void kernel_launch(void* const* d_in, const int* in_sizes, int n_in,
                              void* d_out, int out_size, void* d_ws, size_t ws_size,
                              hipStream_t stream) {
  (void)in_sizes; (void)n_in; (void)out_size; (void)ws_size;
  const int*   x     = (const int*)d_in[0];
  const float* ulook = (const float*)d_in[1];
  const float* ilook = (const float*)d_in[2];
  const float* uW1   = (const float*)d_in[3];
  const float* ub1   = (const float*)d_in[4];
  const float* uW2   = (const float*)d_in[5];
  const float* ub2   = (const float*)d_in[6];
  const float* iW1   = (const float*)d_in[7];
  const float* ib1   = (const float*)d_in[8];
  const float* iW2   = (const float*)d_in[9];
  const float* ib2   = (const float*)d_in[10];
  float* out = (float*)d_out;

  // workspace layout (bytes):
  //   w1s: [2][272][512][8] bf16 = 4,456,448
  //   w2s: [2][64][256][8]  bf16 =   524,288  @ 4,456,448
  //   hsl: [2][8192*512]    bf16 = 16,777,216 @ 4,980,736
  char* ws = (char*)d_ws;
  unsigned short* w1s = (unsigned short*)(ws);
  unsigned short* w2s = (unsigned short*)(ws + 4456448);
  unsigned short* hsl = (unsigned short*)(ws + 4980736);

  ASAECF_tcast<<<dim3(544, 2, 2), 256, 0, stream>>>(uW1, iW1, uW2, iW2, w1s, w2s);
  ASAECF_gemm1<<<dim3(256), 512, 0, stream>>>(x, ulook, ilook, w1s, ub1, ib1, hsl);
  ASAECF_gemm2dot<<<dim3(256), 512, 0, stream>>>(hsl, w2s, ub2, ib2, out);
}